// Round 7
// baseline (217.913 us; speedup 1.0000x reference)
//
#include <hip/hip_runtime.h>
#include <hip/hip_bf16.h>

typedef __attribute__((ext_vector_type(8))) short bf16x8;
typedef __attribute__((ext_vector_type(4))) float f32x4;

__device__ __forceinline__ float sigmoidf_(float v) {
    return 1.0f / (1.0f + __expf(-v));
}
__device__ __forceinline__ short f2bf(float f) {
    union { __hip_bfloat16 h; short s; } cv;
    cv.h = __float2bfloat16(f);
    return cv.s;
}
__device__ __forceinline__ float bf2f(short s) {
    union { float f; unsigned u; } cv;
    cv.u = ((unsigned)(unsigned short)s) << 16;
    return cv.f;
}

// grid barrier: 256 co-resident blocks (grid == CU count, 1 block/CU by LDS).
// Counters zeroed by hipMemsetAsync each launch (workspace is re-poisoned).
__device__ __forceinline__ void gbar(unsigned* ctr) {
    __syncthreads();
    if (threadIdx.x == 0) {
        __threadfence();                       // publish our writes device-wide
        atomicAdd(ctr, 1u);
        while (atomicAdd(ctr, 0u) < 256u) __builtin_amdgcn_s_sleep(1);
        __threadfence();                       // acquire others' writes
    }
    __syncthreads();
}

// ---------------------------------------------------------------------------
// ONE kernel, three phases separated by grid barriers.
//  A: xb cast (all blocks) + weight transposes (blocks 0..135) + hw pack (136)
//  B: gemm C[1024][1024] = xb @ Wt^T  (block = (n-blk, m-blk) of (8,32))
//     [w2s LDS staging issued between barrier0 and gemm — gemm uses no LDS]
//  C: heads (one wave per row) + pair loop (~8 items/block vs staged w2s)
// ---------------------------------------------------------------------------
__global__ __launch_bounds__(256, 2) void mega_kernel(
    const float* __restrict__ x,
    const float* __restrict__ pp_w1, const float* __restrict__ pp_b1,
    const float* __restrict__ pp_w2, const float* __restrict__ pp_b2,
    const float* __restrict__ cd_w1, const float* __restrict__ cd_b1,
    const float* __restrict__ cd_w2, const float* __restrict__ cd_b2,
    const float* __restrict__ cd_w3, const float* __restrict__ cd_b3,
    const float* __restrict__ vel_w, const float* __restrict__ vel_b,
    const float* __restrict__ frc_w, const float* __restrict__ frc_b,
    float* __restrict__ out, float* __restrict__ Ug, float* __restrict__ Vg,
    __hip_bfloat16* __restrict__ xb, __hip_bfloat16* __restrict__ Wt,
    __hip_bfloat16* __restrict__ hidg, __hip_bfloat16* __restrict__ w2t,
    float* __restrict__ hw, unsigned* __restrict__ bar)
{
    __shared__ __align__(16) char smem[65536];  // ts (16.6KB) then w2s (64KB)
    const int blk = blockIdx.x, t = threadIdx.x;
    const int wave = t >> 6, lane = t & 63;
    const int l = lane & 15, q = lane >> 4;

    // ====================== Phase A: conversions ======================
    {   // xb cast: 2048 contiguous elems per block
        int base = blk * 2048 + t * 8;
        float4 a = *(const float4*)(x + base);
        float4 c = *(const float4*)(x + base + 4);
        bf16x8 o;
        o[0] = f2bf(a.x); o[1] = f2bf(a.y); o[2] = f2bf(a.z); o[3] = f2bf(a.w);
        o[4] = f2bf(c.x); o[5] = f2bf(c.y); o[6] = f2bf(c.z); o[7] = f2bf(c.w);
        *(bf16x8*)(xb + base) = o;
    }
    if (blk < 136) {  // one 64x64 transpose tile
        float (*ts)[65] = (float(*)[65])smem;
        const float* src; int ss, k0, n0, region;
        if (blk < 64)       { src = pp_w1; ss = 512; k0 = (blk >> 3) * 64; n0 = (blk & 7) * 64; region = 0; }
        else if (blk < 128) { int i = blk - 64;  src = cd_w1; ss = 256; k0 = (i >> 2) * 64; n0 = (i & 3) * 64; region = 1; }
        else                { int i = blk - 128; src = cd_w2; ss = 128; k0 = (i >> 1) * 64; n0 = (i & 1) * 64; region = 2; }
        #pragma unroll
        for (int i = 0; i < 4; ++i) {
            int r = (t >> 4) + i * 16, c4 = (t & 15) * 4;
            *(float4*)&ts[r][c4] = *(const float4*)(src + (k0 + r) * ss + n0 + c4);
        }
        __syncthreads();
        #pragma unroll
        for (int i = 0; i < 4; ++i) {
            int nOut = (t >> 4) + i * 16, kc = (t & 15) * 4;
            ushort4 o;
            o.x = (unsigned short)f2bf(ts[kc + 0][nOut]);
            o.y = (unsigned short)f2bf(ts[kc + 1][nOut]);
            o.z = (unsigned short)f2bf(ts[kc + 2][nOut]);
            o.w = (unsigned short)f2bf(ts[kc + 3][nOut]);
            int gn = n0 + nOut, gk = k0 + kc;
            if (region == 0)      *(ushort4*)(Wt + gn * 512 + gk) = o;
            else if (region == 1) {
                int row = (gk < 512) ? (512 + gn) : (768 + gn);
                *(ushort4*)(Wt + row * 512 + (gk & 511)) = o;
            } else                *(ushort4*)(w2t + gn * 256 + gk) = o;
        }
    } else if (blk == 136) {  // hw pack
        for (int e = t; e < 5120; e += 256) {
            int h = e >> 9, k = e & 511;
            float v = (h < 4) ? pp_w2[k * 128 + h]
                    : (h < 7) ? vel_w[k * 3 + (h - 4)]
                              : frc_w[k * 3 + (h - 7)];
            hw[e] = v;
        }
    }
    gbar(bar + 0);

    // stage w2s[g=k/8][n] (conflict-free B-frag reads); overlaps phase B.
    {
        short* w2s = (short*)smem;
        #pragma unroll
        for (int it = 0; it < 16; ++it) {
            int e = it * 256 + t;            // uint4 index, 4096 total
            int n = e >> 5, g = e & 31;
            uint4 d = *(const uint4*)(w2t + n * 256 + g * 8);
            *(uint4*)(w2s + (g * 128 + n) * 8) = d;
        }
    }

    // ====================== Phase B: gemm ======================
    {
        const int m0 = (blk >> 3) * 32;
        const int n0 = (blk & 7) * 128 + wave * 32;
        const __hip_bfloat16* a0p = xb + (m0 + l) * 512 + q * 8;
        const __hip_bfloat16* a1p = a0p + 16 * 512;
        const __hip_bfloat16* b0p = Wt + (n0 + l) * 512 + q * 8;
        const __hip_bfloat16* b1p = b0p + 16 * 512;
        f32x4 acc00 = {}, acc01 = {}, acc10 = {}, acc11 = {};
        #pragma unroll
        for (int ks = 0; ks < 16; ++ks) {
            bf16x8 a0 = *(const bf16x8*)(a0p + ks * 32);
            bf16x8 a1 = *(const bf16x8*)(a1p + ks * 32);
            bf16x8 b0 = *(const bf16x8*)(b0p + ks * 32);
            bf16x8 b1 = *(const bf16x8*)(b1p + ks * 32);
            acc00 = __builtin_amdgcn_mfma_f32_16x16x32_bf16(a0, b0, acc00, 0, 0, 0);
            acc01 = __builtin_amdgcn_mfma_f32_16x16x32_bf16(a0, b1, acc01, 0, 0, 0);
            acc10 = __builtin_amdgcn_mfma_f32_16x16x32_bf16(a1, b0, acc10, 0, 0, 0);
            acc11 = __builtin_amdgcn_mfma_f32_16x16x32_bf16(a1, b1, acc11, 0, 0, 0);
        }
        const int c0 = n0 + l, c1 = n0 + 16 + l;
        #pragma unroll
        for (int mt = 0; mt < 2; ++mt) {
            const f32x4& A0 = mt ? acc10 : acc00;
            const f32x4& A1 = mt ? acc11 : acc01;
            if (n0 < 512) {
                float b0v = pp_b1[c0], b1v = pp_b1[c1];
                #pragma unroll
                for (int r = 0; r < 4; ++r) {
                    int rg = m0 + mt * 16 + q * 4 + r;
                    hidg[rg * 512 + c0] = __float2bfloat16(fmaxf(A0[r] + b0v, 0.f));
                    hidg[rg * 512 + c1] = __float2bfloat16(fmaxf(A1[r] + b1v, 0.f));
                }
            } else if (n0 < 768) {
                float b0v = cd_b1[c0 - 512], b1v = cd_b1[c1 - 512];
                #pragma unroll
                for (int r = 0; r < 4; ++r) {
                    int rg = m0 + mt * 16 + q * 4 + r;
                    Ug[rg * 256 + (c0 - 512)] = A0[r] + b0v;
                    Ug[rg * 256 + (c1 - 512)] = A1[r] + b1v;
                }
            } else {
                #pragma unroll
                for (int r = 0; r < 4; ++r) {
                    int rg = m0 + mt * 16 + q * 4 + r;
                    Vg[rg * 256 + (c0 - 768)] = A0[r];
                    Vg[rg * 256 + (c1 - 768)] = A1[r];
                }
            }
        }
    }
    gbar(bar + 1);

    // ====================== Phase C: heads + pairs ======================
    {   // heads: one wave per row (row = blk*4 + wave)
        const int row = blk * 4 + wave;
        const float4* xr = (const float4*)(x + row * 512);
        float4 xa = xr[lane * 2], xc = xr[lane * 2 + 1];
        bf16x8 hb = *(const bf16x8*)(hidg + row * 512 + lane * 8);
        float hf[8];
        #pragma unroll
        for (int j = 0; j < 8; ++j) hf[j] = bf2f(hb[j]);
        #pragma unroll
        for (int h = 0; h < 10; ++h) {
            const float4* wr = (const float4*)(hw + h * 512);
            float4 wa = wr[lane * 2], wc = wr[lane * 2 + 1];
            float s;
            if (h < 4) {
                s = hf[0]*wa.x + hf[1]*wa.y + hf[2]*wa.z + hf[3]*wa.w
                  + hf[4]*wc.x + hf[5]*wc.y + hf[6]*wc.z + hf[7]*wc.w;
            } else {
                s = xa.x*wa.x + xa.y*wa.y + xa.z*wa.z + xa.w*wa.w
                  + xc.x*wc.x + xc.y*wc.y + xc.z*wc.z + xc.w*wc.w;
            }
            s += __shfl_xor(s, 1);  s += __shfl_xor(s, 2);
            s += __shfl_xor(s, 4);  s += __shfl_xor(s, 8);
            s += __shfl_xor(s, 16); s += __shfl_xor(s, 32);
            if (lane == 0) {
                if (h < 4) {
                    float sg = sigmoidf_(s + pp_b2[h]);
                    out[h * 1024 + row] = (h == 0) ? sg * 100.f : (h == 3) ? sg * 10.f : sg;
                } else if (h < 7) {
                    out[4096 + row * 3 + (h - 4)] = s + vel_b[h - 4];
                } else {
                    out[7168 + row * 3 + (h - 7)] = s + frc_b[h - 7];
                }
            }
        }
    }

    {   // pair loop: 2112 items (tp 0..527 x batch 0..3), ~8 per block.
        // Wave = one quadrant (16 slots) x all 128 cols; w2s reused across items.
        const short* w2s = (const short*)smem;
        float b2v[8], w3v[8];
        #pragma unroll
        for (int nt = 0; nt < 8; ++nt) {
            b2v[nt] = cd_b2[nt * 16 + l];
            w3v[nt] = cd_w3[nt * 16 + l];
        }
        const float b3 = cd_b3[0];
        for (int item = blk; item < 2112; item += 256) {
            const int tp = item >> 2, b = item & 3;
            int ti = 0;
            while ((ti + 1) * (65 - (ti + 1)) / 2 <= tp) ++ti;
            const int tj = ti + (tp - ti * (65 - ti) / 2);
            const int i0 = ti * 8, j0 = tj * 8;

            const int pb = wave * 16 + l;        // slot whose h-row lane builds
            const float* Up = Ug + (b * 256 + i0 + (pb >> 3)) * 256;
            const float* Vp = Vg + (b * 256 + j0 + (pb & 7)) * 256;

            f32x4 acc[8] = {};
            #pragma unroll
            for (int ks = 0; ks < 8; ++ks) {
                const int kk = ks * 32 + q * 8;
                float4 u0 = *(const float4*)(Up + kk);
                float4 u1 = *(const float4*)(Up + kk + 4);
                float4 v0 = *(const float4*)(Vp + kk);
                float4 v1 = *(const float4*)(Vp + kk + 4);
                bf16x8 afr;
                afr[0] = f2bf(fmaxf(u0.x + v0.x, 0.f));
                afr[1] = f2bf(fmaxf(u0.y + v0.y, 0.f));
                afr[2] = f2bf(fmaxf(u0.z + v0.z, 0.f));
                afr[3] = f2bf(fmaxf(u0.w + v0.w, 0.f));
                afr[4] = f2bf(fmaxf(u1.x + v1.x, 0.f));
                afr[5] = f2bf(fmaxf(u1.y + v1.y, 0.f));
                afr[6] = f2bf(fmaxf(u1.z + v1.z, 0.f));
                afr[7] = f2bf(fmaxf(u1.w + v1.w, 0.f));
                const short* wg = w2s + (ks * 4 + q) * 1024;   // granule block
                #pragma unroll
                for (int nt = 0; nt < 8; ++nt) {
                    bf16x8 bfr = *(const bf16x8*)(wg + (nt * 16 + l) * 8);
                    acc[nt] = __builtin_amdgcn_mfma_f32_16x16x32_bf16(afr, bfr, acc[nt], 0, 0, 0);
                }
            }

            float* base = out + 10240 + b * 65536;
            #pragma unroll
            for (int r = 0; r < 4; ++r) {
                float s = 0.f;
                #pragma unroll
                for (int nt = 0; nt < 8; ++nt)
                    s += fmaxf(acc[nt][r] + b2v[nt], 0.f) * w3v[nt];
                s += __shfl_xor(s, 1);
                s += __shfl_xor(s, 2);
                s += __shfl_xor(s, 4);
                s += __shfl_xor(s, 8);
                if (l == 0) {
                    const int p = wave * 16 + q * 4 + r;
                    const int i = i0 + (p >> 3), j = j0 + (p & 7);
                    float prob = sigmoidf_(s + b3);
                    if (i < j) {
                        base[i * 256 + j] = prob;
                        base[j * 256 + i] = prob;
                    } else if (i == j) {
                        base[i * 256 + i] = 0.0f;
                    }
                }
            }
        }
    }
}

// ---------------------------------------------------------------------------
extern "C" void kernel_launch(void* const* d_in, const int* in_sizes, int n_in,
                              void* d_out, int out_size, void* d_ws, size_t ws_size,
                              hipStream_t stream) {
    const float* x     = (const float*)d_in[0];
    const float* pp_w1 = (const float*)d_in[1];
    const float* pp_b1 = (const float*)d_in[2];
    const float* pp_w2 = (const float*)d_in[3];
    const float* pp_b2 = (const float*)d_in[4];
    const float* cd_w1 = (const float*)d_in[5];
    const float* cd_b1 = (const float*)d_in[6];
    const float* cd_w2 = (const float*)d_in[7];
    const float* cd_b2 = (const float*)d_in[8];
    const float* cd_w3 = (const float*)d_in[9];
    const float* cd_b3 = (const float*)d_in[10];
    const float* vel_w = (const float*)d_in[11];
    const float* vel_b = (const float*)d_in[12];
    const float* frc_w = (const float*)d_in[13];
    const float* frc_b = (const float*)d_in[14];

    float* out = (float*)d_out;
    // ws: Ug 1MB | Vg 1MB | xb 1MB | Wt 1MB | hidg 1MB | w2t 64KB | hw 20KB
    // barrier counters at 8MB (zeroed on-stream each launch; ws is poisoned)
    float* Ug = (float*)d_ws;
    float* Vg = Ug + 262144;
    __hip_bfloat16* xb   = (__hip_bfloat16*)(Vg + 262144);
    __hip_bfloat16* Wt   = xb + 524288;
    __hip_bfloat16* hidg = Wt + 524288;
    __hip_bfloat16* w2t  = hidg + 524288;
    float* hw = (float*)(w2t + 32768);
    unsigned* bar = (unsigned*)((char*)d_ws + (8u << 20));

    hipMemsetAsync(bar, 0, 256, stream);
    mega_kernel<<<dim3(256), dim3(256), 0, stream>>>(
        x, pp_w1, pp_b1, pp_w2, pp_b2, cd_w1, cd_b1, cd_w2, cd_b2,
        cd_w3, cd_b3, vel_w, vel_b, frc_w, frc_b,
        out, Ug, Vg, xb, Wt, hidg, w2t, hw, bar);
}

// Round 10
// 154.091 us; speedup vs baseline: 1.4142x; 1.4142x over previous
//
#include <hip/hip_runtime.h>
#include <hip/hip_bf16.h>

typedef __attribute__((ext_vector_type(8))) short bf16x8;
typedef __attribute__((ext_vector_type(4))) float f32x4;

__device__ __forceinline__ float sigmoidf_(float v) {
    return 1.0f / (1.0f + __expf(-v));
}
__device__ __forceinline__ short f2bf(float f) {
    union { __hip_bfloat16 h; short s; } cv;
    cv.h = __float2bfloat16(f);
    return cv.s;
}
__device__ __forceinline__ float bf2f(short s) {
    union { float f; unsigned u; } cv;
    cv.u = ((unsigned)(unsigned short)s) << 16;
    return cv.f;
}

// ---------------------------------------------------------------------------
// Kernel 0: conversions, all coalesced. (unchanged from r6)
// ---------------------------------------------------------------------------
__global__ __launch_bounds__(256) void convert_kernel(
    const float* __restrict__ x, const float* __restrict__ pp_w1,
    const float* __restrict__ cd_w1, const float* __restrict__ cd_w2,
    const float* __restrict__ pp_w2, const float* __restrict__ vel_w,
    const float* __restrict__ frc_w,
    __hip_bfloat16* __restrict__ xb, __hip_bfloat16* __restrict__ Wt,
    __hip_bfloat16* __restrict__ w2t, float* __restrict__ hw)
{
    __shared__ float ts[64][65];
    const int b = blockIdx.x, t = threadIdx.x;

    if (b < 256) {  // xb cast
        int base = b * 2048 + t * 8;
        float4 a = *(const float4*)(x + base);
        float4 c = *(const float4*)(x + base + 4);
        bf16x8 o;
        o[0] = f2bf(a.x); o[1] = f2bf(a.y); o[2] = f2bf(a.z); o[3] = f2bf(a.w);
        o[4] = f2bf(c.x); o[5] = f2bf(c.y); o[6] = f2bf(c.z); o[7] = f2bf(c.w);
        *(bf16x8*)(xb + base) = o;
        return;
    }
    if (b == 392) {  // hw pack
        for (int e = t; e < 5120; e += 256) {
            int h = e >> 9, k = e & 511;
            float v = (h < 4) ? pp_w2[k * 128 + h]
                    : (h < 7) ? vel_w[k * 3 + (h - 4)]
                              : frc_w[k * 3 + (h - 7)];
            hw[e] = v;
        }
        return;
    }

    const float* src; int ss, k0, n0, region;
    if (b < 320)      { int i = b - 256; src = pp_w1; ss = 512; k0 = (i >> 3) * 64; n0 = (i & 7) * 64; region = 0; }
    else if (b < 384) { int i = b - 320; src = cd_w1; ss = 256; k0 = (i >> 2) * 64; n0 = (i & 3) * 64; region = 1; }
    else              { int i = b - 384; src = cd_w2; ss = 128; k0 = (i >> 1) * 64; n0 = (i & 1) * 64; region = 2; }

    #pragma unroll
    for (int i = 0; i < 4; ++i) {
        int r = (t >> 4) + i * 16, c4 = (t & 15) * 4;
        *(float4*)&ts[r][c4] = *(const float4*)(src + (k0 + r) * ss + n0 + c4);
    }
    __syncthreads();
    #pragma unroll
    for (int i = 0; i < 4; ++i) {
        int nOut = (t >> 4) + i * 16, kc = (t & 15) * 4;
        ushort4 o;
        o.x = (unsigned short)f2bf(ts[kc + 0][nOut]);
        o.y = (unsigned short)f2bf(ts[kc + 1][nOut]);
        o.z = (unsigned short)f2bf(ts[kc + 2][nOut]);
        o.w = (unsigned short)f2bf(ts[kc + 3][nOut]);
        int gn = n0 + nOut, gk = k0 + kc;
        if (region == 0)      *(ushort4*)(Wt + gn * 512 + gk) = o;
        else if (region == 1) {
            int row = (gk < 512) ? (512 + gn) : (768 + gn);
            *(ushort4*)(Wt + row * 512 + (gk & 511)) = o;
        } else                *(ushort4*)(w2t + gn * 256 + gk) = o;
    }
}

// ---------------------------------------------------------------------------
// Kernel 1: MFMA GEMM C[1024][1024] = xb @ Wt^T. 2x2 tiles/wave, grid (8,32).
// (unchanged — best measured config)
// ---------------------------------------------------------------------------
__global__ __launch_bounds__(256) void gemm_kernel(
    const __hip_bfloat16* __restrict__ xb, const __hip_bfloat16* __restrict__ Wt,
    const float* __restrict__ pp_b1, const float* __restrict__ cd_b1,
    __hip_bfloat16* __restrict__ hidg, float* __restrict__ Ug,
    float* __restrict__ Vg)
{
    const int t = threadIdx.x;
    const int wave = t >> 6, lane = t & 63;
    const int l = lane & 15, q = lane >> 4;
    const int m0 = blockIdx.y * 32;
    const int n0 = blockIdx.x * 128 + wave * 32;

    const __hip_bfloat16* a0p = xb + (m0 + l) * 512 + q * 8;
    const __hip_bfloat16* a1p = a0p + 16 * 512;
    const __hip_bfloat16* b0p = Wt + (n0 + l) * 512 + q * 8;
    const __hip_bfloat16* b1p = b0p + 16 * 512;

    f32x4 acc00 = {}, acc01 = {}, acc10 = {}, acc11 = {};
    #pragma unroll
    for (int ks = 0; ks < 16; ++ks) {
        bf16x8 a0 = *(const bf16x8*)(a0p + ks * 32);
        bf16x8 a1 = *(const bf16x8*)(a1p + ks * 32);
        bf16x8 b0 = *(const bf16x8*)(b0p + ks * 32);
        bf16x8 b1 = *(const bf16x8*)(b1p + ks * 32);
        acc00 = __builtin_amdgcn_mfma_f32_16x16x32_bf16(a0, b0, acc00, 0, 0, 0);
        acc01 = __builtin_amdgcn_mfma_f32_16x16x32_bf16(a0, b1, acc01, 0, 0, 0);
        acc10 = __builtin_amdgcn_mfma_f32_16x16x32_bf16(a1, b0, acc10, 0, 0, 0);
        acc11 = __builtin_amdgcn_mfma_f32_16x16x32_bf16(a1, b1, acc11, 0, 0, 0);
    }

    const int c0 = n0 + l, c1 = n0 + 16 + l;
    #pragma unroll
    for (int mt = 0; mt < 2; ++mt) {
        const f32x4& A0 = mt ? acc10 : acc00;
        const f32x4& A1 = mt ? acc11 : acc01;
        if (n0 < 512) {
            float b0v = pp_b1[c0], b1v = pp_b1[c1];
            #pragma unroll
            for (int r = 0; r < 4; ++r) {
                int rg = m0 + mt * 16 + q * 4 + r;
                hidg[rg * 512 + c0] = __float2bfloat16(fmaxf(A0[r] + b0v, 0.f));
                hidg[rg * 512 + c1] = __float2bfloat16(fmaxf(A1[r] + b1v, 0.f));
            }
        } else if (n0 < 768) {
            float b0v = cd_b1[c0 - 512], b1v = cd_b1[c1 - 512];
            #pragma unroll
            for (int r = 0; r < 4; ++r) {
                int rg = m0 + mt * 16 + q * 4 + r;
                Ug[rg * 256 + (c0 - 512)] = A0[r] + b0v;
                Ug[rg * 256 + (c1 - 512)] = A1[r] + b1v;
            }
        } else {
            #pragma unroll
            for (int r = 0; r < 4; ++r) {
                int rg = m0 + mt * 16 + q * 4 + r;
                Vg[rg * 256 + (c0 - 768)] = A0[r];
                Vg[rg * 256 + (c1 - 768)] = A1[r];
            }
        }
    }
}

// ---------------------------------------------------------------------------
// Kernel 2: tail = pair MLP v6 + heads, one launch, ZERO LDS, zero barriers.
// Pair: grid.x<528: 256 thr = 4 waves; wave = 32 slots x all 128 cols of one
// (tile, batch): batch = bz*2 + (w>>1), slot base s0 = (w&1)*32.
// A-frags built in regs from global U/V; B-frags straight from L2 w2t.
// acc = 2x8 f32x4 = 64 VGPR; launch_bounds(256,3) caps VGPR (no spill).
// Heads: grid.x>=528: one wave per row, 10 shuffle-reduce dots.
// ---------------------------------------------------------------------------
__global__ __launch_bounds__(256, 3) void tail_kernel(
    const float* __restrict__ x, const __hip_bfloat16* __restrict__ hidg,
    const float* __restrict__ hw, const float* __restrict__ pp_b2,
    const float* __restrict__ vel_b, const float* __restrict__ frc_b,
    const float* __restrict__ Ug, const float* __restrict__ Vg,
    const __hip_bfloat16* __restrict__ w2t,
    const float* __restrict__ cd_b2, const float* __restrict__ cd_w3,
    const float* __restrict__ cd_b3, float* __restrict__ out)
{
    const int bx = blockIdx.x, bz = blockIdx.y, t = threadIdx.x;
    const int w = t >> 6, lane = t & 63;
    const int l = lane & 15, q = lane >> 4;

    if (bx >= 528) {  // ---------------- heads ----------------
        const int idx = (bx - 528) + 128 * bz;   // 0..255
        const int row = idx * 4 + w;             // 0..1023
        const float4* xr = (const float4*)(x + row * 512);
        float4 xa = xr[lane * 2], xc = xr[lane * 2 + 1];
        bf16x8 hb = *(const bf16x8*)(hidg + row * 512 + lane * 8);
        float hf[8];
        #pragma unroll
        for (int j = 0; j < 8; ++j) hf[j] = bf2f(hb[j]);
        #pragma unroll
        for (int h = 0; h < 10; ++h) {
            const float4* wr = (const float4*)(hw + h * 512);
            float4 wa = wr[lane * 2], wc = wr[lane * 2 + 1];
            float s;
            if (h < 4) {
                s = hf[0]*wa.x + hf[1]*wa.y + hf[2]*wa.z + hf[3]*wa.w
                  + hf[4]*wc.x + hf[5]*wc.y + hf[6]*wc.z + hf[7]*wc.w;
            } else {
                s = xa.x*wa.x + xa.y*wa.y + xa.z*wa.z + xa.w*wa.w
                  + xc.x*wc.x + xc.y*wc.y + xc.z*wc.z + xc.w*wc.w;
            }
            s += __shfl_xor(s, 1);  s += __shfl_xor(s, 2);
            s += __shfl_xor(s, 4);  s += __shfl_xor(s, 8);
            s += __shfl_xor(s, 16); s += __shfl_xor(s, 32);
            if (lane == 0) {
                if (h < 4) {
                    float sg = sigmoidf_(s + pp_b2[h]);
                    out[h * 1024 + row] = (h == 0) ? sg * 100.f : (h == 3) ? sg * 10.f : sg;
                } else if (h < 7) {
                    out[4096 + row * 3 + (h - 4)] = s + vel_b[h - 4];
                } else {
                    out[7168 + row * 3 + (h - 7)] = s + frc_b[h - 7];
                }
            }
        }
        return;
    }

    // ---------------- pair ----------------
    const int tp = bx;
    int ti = 0;
    while ((ti + 1) * (65 - (ti + 1)) / 2 <= tp) ++ti;
    const int tj = ti + (tp - ti * (65 - ti) / 2);
    const int i0 = ti * 8, j0 = tj * 8;

    const int b = bz * 2 + (w >> 1);     // batch 0..3
    const int s0 = (w & 1) * 32;         // slot base of this wave

    const int pA = s0 + l, pB = pA + 16;
    const float* UA = Ug + (b * 256 + i0 + (pA >> 3)) * 256;
    const float* VA = Vg + (b * 256 + j0 + (pA & 7)) * 256;
    const float* UB = Ug + (b * 256 + i0 + (pB >> 3)) * 256;
    const float* VB = Vg + (b * 256 + j0 + (pB & 7)) * 256;
    const __hip_bfloat16* wB = w2t + l * 256 + q * 8;  // + nt*4096 + ks*32

    f32x4 acc0[8] = {}, acc1[8] = {};
    #pragma unroll
    for (int ks = 0; ks < 8; ++ks) {
        const int kk = ks * 32 + q * 8;
        float4 ua0 = *(const float4*)(UA + kk), ua1 = *(const float4*)(UA + kk + 4);
        float4 va0 = *(const float4*)(VA + kk), va1 = *(const float4*)(VA + kk + 4);
        bf16x8 afrA;
        afrA[0] = f2bf(fmaxf(ua0.x + va0.x, 0.f));
        afrA[1] = f2bf(fmaxf(ua0.y + va0.y, 0.f));
        afrA[2] = f2bf(fmaxf(ua0.z + va0.z, 0.f));
        afrA[3] = f2bf(fmaxf(ua0.w + va0.w, 0.f));
        afrA[4] = f2bf(fmaxf(ua1.x + va1.x, 0.f));
        afrA[5] = f2bf(fmaxf(ua1.y + va1.y, 0.f));
        afrA[6] = f2bf(fmaxf(ua1.z + va1.z, 0.f));
        afrA[7] = f2bf(fmaxf(ua1.w + va1.w, 0.f));
        float4 ub0 = *(const float4*)(UB + kk), ub1 = *(const float4*)(UB + kk + 4);
        float4 vb0 = *(const float4*)(VB + kk), vb1 = *(const float4*)(VB + kk + 4);
        bf16x8 afrB;
        afrB[0] = f2bf(fmaxf(ub0.x + vb0.x, 0.f));
        afrB[1] = f2bf(fmaxf(ub0.y + vb0.y, 0.f));
        afrB[2] = f2bf(fmaxf(ub0.z + vb0.z, 0.f));
        afrB[3] = f2bf(fmaxf(ub0.w + vb0.w, 0.f));
        afrB[4] = f2bf(fmaxf(ub1.x + vb1.x, 0.f));
        afrB[5] = f2bf(fmaxf(ub1.y + vb1.y, 0.f));
        afrB[6] = f2bf(fmaxf(ub1.z + vb1.z, 0.f));
        afrB[7] = f2bf(fmaxf(ub1.w + vb1.w, 0.f));
        #pragma unroll
        for (int nt = 0; nt < 8; ++nt) {
            bf16x8 bfr = *(const bf16x8*)(wB + nt * 4096 + ks * 32);
            acc0[nt] = __builtin_amdgcn_mfma_f32_16x16x32_bf16(afrA, bfr, acc0[nt], 0, 0, 0);
            acc1[nt] = __builtin_amdgcn_mfma_f32_16x16x32_bf16(afrB, bfr, acc1[nt], 0, 0, 0);
        }
    }

    // In-wave epilogue: layer 3 + 16-lane reduce + symmetric scatter.
    float b2v[8], w3v[8];
    #pragma unroll
    for (int nt = 0; nt < 8; ++nt) {
        b2v[nt] = cd_b2[nt * 16 + l];
        w3v[nt] = cd_w3[nt * 16 + l];
    }
    const float b3 = cd_b3[0];
    float* base = out + 10240 + b * 65536;
    #pragma unroll
    for (int mt = 0; mt < 2; ++mt) {
        #pragma unroll
        for (int r = 0; r < 4; ++r) {
            // D layout: slot = s0 + mt*16 + q*4 + r, col = nt*16 + l
            float s = 0.f;
            #pragma unroll
            for (int nt = 0; nt < 8; ++nt) {
                const f32x4& a = mt ? acc1[nt] : acc0[nt];
                s += fmaxf(a[r] + b2v[nt], 0.f) * w3v[nt];
            }
            s += __shfl_xor(s, 1);
            s += __shfl_xor(s, 2);
            s += __shfl_xor(s, 4);
            s += __shfl_xor(s, 8);
            if (l == 0) {
                const int p = s0 + mt * 16 + q * 4 + r;
                const int i = i0 + (p >> 3), j = j0 + (p & 7);
                float prob = sigmoidf_(s + b3);
                if (i < j) {
                    base[i * 256 + j] = prob;
                    base[j * 256 + i] = prob;
                } else if (i == j) {
                    base[i * 256 + i] = 0.0f;
                }
            }
        }
    }
}

// ---------------------------------------------------------------------------
extern "C" void kernel_launch(void* const* d_in, const int* in_sizes, int n_in,
                              void* d_out, int out_size, void* d_ws, size_t ws_size,
                              hipStream_t stream) {
    const float* x     = (const float*)d_in[0];
    const float* pp_w1 = (const float*)d_in[1];
    const float* pp_b1 = (const float*)d_in[2];
    const float* pp_w2 = (const float*)d_in[3];
    const float* pp_b2 = (const float*)d_in[4];
    const float* cd_w1 = (const float*)d_in[5];
    const float* cd_b1 = (const float*)d_in[6];
    const float* cd_w2 = (const float*)d_in[7];
    const float* cd_b2 = (const float*)d_in[8];
    const float* cd_w3 = (const float*)d_in[9];
    const float* cd_b3 = (const float*)d_in[10];
    const float* vel_w = (const float*)d_in[11];
    const float* vel_b = (const float*)d_in[12];
    const float* frc_w = (const float*)d_in[13];
    const float* frc_b = (const float*)d_in[14];

    float* out = (float*)d_out;
    // ws: Ug 1MB | Vg 1MB | xb 1MB | Wt 1MB | hidg 1MB | w2t 64KB | hw 20KB
    float* Ug = (float*)d_ws;
    float* Vg = Ug + 262144;
    __hip_bfloat16* xb   = (__hip_bfloat16*)(Vg + 262144);
    __hip_bfloat16* Wt   = xb + 524288;
    __hip_bfloat16* hidg = Wt + 524288;
    __hip_bfloat16* w2t  = hidg + 524288;
    float* hw = (float*)(w2t + 32768);

    convert_kernel<<<dim3(393), dim3(256), 0, stream>>>(
        x, pp_w1, cd_w1, cd_w2, pp_w2, vel_w, frc_w, xb, Wt, w2t, hw);
    gemm_kernel<<<dim3(8, 32), dim3(256), 0, stream>>>(
        xb, Wt, pp_b1, cd_b1, hidg, Ug, Vg);
    tail_kernel<<<dim3(656, 2), dim3(256), 0, stream>>>(
        x, hidg, hw, pp_b2, vel_b, frc_b,
        Ug, Vg, w2t, cd_b2, cd_w3, cd_b3, out);
}